// Round 2
// baseline (9726.575 us; speedup 1.0000x reference)
//
#include <hip/hip_runtime.h>
#include <stdint.h>
#include <math.h>

// plmDCA one Gibbs sweep — bitwise-faithful replay of the JAX reference.
// Confirmed (round 1, absmax 0.0): partitionable threefry (o0^o1), Eigen
// KC=288 k-blocked left-fold sum order, f64-computed f32-rounded logs.
//
// Round 2: instruction-count reduction.
//  - states packed 4/dword in LDS (1 ds_read per 4 elements)
//  - KC-crossing check only at the 18 candidate l's (constexpr table + full
//    unroll folds it away elsewhere); thr(m) = 288m mod 21 at l=floor(288m/21)
//  - SPB 32 -> 8: 1024 blocks, 4 blocks/CU, independent barrier groups

#define NSEQ 8192
#define LRES 256
#define QST  21
#define SPB  8                 // sequences per block
#define NTHREADS (SPB * QST)   // 168

// Per-l KC-crossing table: 255 = plain add; else threshold on b for boundary m.
struct KcTbl {
  unsigned char thr[LRES];
  constexpr KcTbl() : thr() {
    for (int i = 0; i < LRES; ++i) thr[i] = 255;
    for (int m = 1; m < 19; ++m) {
      int l = (288 * m) / 21;
      thr[l] = (unsigned char)(288 * m - 21 * l);
    }
  }
};
static constexpr KcTbl KC_TBL{};

__device__ __forceinline__ uint32_t rotl32(uint32_t v, uint32_t r) {
  return (v << r) | (v >> (32u - r));
}

// JAX/Random123 Threefry-2x32, 20 rounds.
__device__ __forceinline__ void threefry2x32(uint32_t k0, uint32_t k1,
                                             uint32_t c0, uint32_t c1,
                                             uint32_t& o0, uint32_t& o1) {
  uint32_t ks2 = k0 ^ k1 ^ 0x1BD11BDAu;
  uint32_t x0 = c0 + k0;
  uint32_t x1 = c1 + k1;
#define TF_ROUND(r) { x0 += x1; x1 = rotl32(x1, r); x1 ^= x0; }
  TF_ROUND(13u) TF_ROUND(15u) TF_ROUND(26u) TF_ROUND(6u)
  x0 += k1;  x1 += ks2 + 1u;
  TF_ROUND(17u) TF_ROUND(29u) TF_ROUND(16u) TF_ROUND(24u)
  x0 += ks2; x1 += k0 + 2u;
  TF_ROUND(13u) TF_ROUND(15u) TF_ROUND(26u) TF_ROUND(6u)
  x0 += k0;  x1 += k1 + 3u;
  TF_ROUND(17u) TF_ROUND(29u) TF_ROUND(16u) TF_ROUND(24u)
  x0 += k1;  x1 += ks2 + 4u;
  TF_ROUND(13u) TF_ROUND(15u) TF_ROUND(26u) TF_ROUND(6u)
  x0 += ks2; x1 += k0 + 5u;
#undef TF_ROUND
  o0 = x0; o1 = x1;
}

// JAX gumbel: -log(-log(uniform(tiny,1))), logs f64-computed f32-rounded.
__device__ __forceinline__ float gumbel_f32(uint32_t bits) {
  float f = __uint_as_float((bits >> 9) | 0x3f800000u) - 1.0f;
  float u = fmaxf(1.17549435e-38f, f + 1.17549435e-38f);
  float w = (float)log((double)u);
  float t = -w;
  float g = -(float)log((double)t);
  return g;
}

__global__ __launch_bounds__(NTHREADS)
void gibbs_sweep(const float* __restrict__ X, const int* __restrict__ order,
                 const float* __restrict__ h, const float* __restrict__ J,
                 const float* __restrict__ betaPtr, float* __restrict__ out) {
  __shared__ uint32_t sbst[(LRES / 4) * SPB];  // packed states: word (l>>2)*SPB+s
  __shared__ float    vals[QST][SPB];

  const int nl  = threadIdx.x;       // 0..7   local sequence
  const int a   = threadIdx.y;       // 0..20  category
  const int tid = nl + SPB * a;      // 0..167
  const int n0  = blockIdx.x * SPB;
  const int n   = n0 + nl;
  const float beta = betaPtr[0];

  // ---- init packed state from one-hot X ----
  for (int idx = tid; idx < (LRES / 4) * SPB; idx += NTHREADS) {
    int s  = idx & (SPB - 1);
    int wg = idx >> 3;               // word group: covers l = 4wg..4wg+3
    uint32_t w = 0;
#pragma unroll
    for (int j = 0; j < 4; ++j) {
      int l = 4 * wg + j;
      const float* xp = X + ((size_t)(n0 + s) * LRES + l) * QST;
      int b = 0;
#pragma unroll
      for (int q = 0; q < QST; ++q) b = (xp[q] > 0.5f) ? q : b;
      w |= ((uint32_t)b) << (8 * j);
    }
    sbst[wg * SPB + s] = w;
  }
  __syncthreads();

  // ---- sequential Gibbs sweep ----
  for (int t = 0; t < LRES; ++t) {
    const int i = order[t];
    const uint32_t rowoff = (uint32_t)(i * QST + a) * (uint32_t)(LRES * QST);

    // dot over l, Eigen KC=288 k-blocked left-fold order.
    float tot = 0.0f, part = 0.0f;
#pragma unroll
    for (int lg = 0; lg < LRES / 4; ++lg) {
      uint32_t w = sbst[lg * SPB + nl];
#pragma unroll
      for (int j = 0; j < 4; ++j) {
        const int l = 4 * lg + j;
        uint32_t b = (w >> (8 * j)) & 0xffu;
        float jv = J[rowoff + (uint32_t)(l * QST) + b];
        const int thr = KC_TBL.thr[l];          // folds at compile time
        if (thr == 255) {
          part += jv;
        } else if (thr == 0) {                  // exact boundary (m=7,14)
          tot += part; part = jv;
        } else {
          if ((int)b >= thr) { tot += part; part = jv; }
          else               { part += jv; tot += part; part = 0.0f; }
        }
      }
    }
    tot += part;

    float lo = h[i * QST + a] + tot;

    uint32_t kk0, kk1, o0, o1;
    threefry2x32(0u, 42u, 0u, (uint32_t)t, kk0, kk1);
    threefry2x32(kk0, kk1, 0u, (uint32_t)(n * QST + a), o0, o1);
    float g = gumbel_f32(o0 ^ o1);

    vals[a][nl] = g + beta * lo;
    __syncthreads();

    if (a == 0) {                               // first-max argmax over 21
      float best = vals[0][nl];
      int bi = 0;
#pragma unroll
      for (int q = 1; q < QST; ++q) {
        float vv = vals[q][nl];
        if (vv > best) { best = vv; bi = q; }
      }
      // byte-update packed state for residue i, sequence nl
      unsigned char* bp = reinterpret_cast<unsigned char*>(sbst);
      bp[((i >> 2) * SPB + nl) * 4 + (i & 3)] = (unsigned char)bi;
    }
    __syncthreads();
  }

  // ---- expand packed state to one-hot f32 output ----
  const size_t base = (size_t)n0 * LRES * QST;
  for (int idx = tid; idx < SPB * LRES * QST; idx += NTHREADS) {
    int s   = idx / (LRES * QST);
    int rem = idx - s * (LRES * QST);
    int l   = rem / QST;
    int q   = rem - l * QST;
    uint32_t w = sbst[(l >> 2) * SPB + s];
    int b = (int)((w >> (8 * (l & 3))) & 0xffu);
    out[base + idx] = (b == q) ? 1.0f : 0.0f;
  }
}

extern "C" void kernel_launch(void* const* d_in, const int* in_sizes, int n_in,
                              void* d_out, int out_size, void* d_ws, size_t ws_size,
                              hipStream_t stream) {
  const float* X     = (const float*)d_in[0];
  const int*   order = (const int*)  d_in[1];
  const float* h     = (const float*)d_in[2];
  const float* J     = (const float*)d_in[3];
  const float* beta  = (const float*)d_in[4];
  float* out = (float*)d_out;

  dim3 grid(NSEQ / SPB);      // 1024 blocks
  dim3 block(SPB, QST);       // 8 x 21 = 168 threads
  hipLaunchKernelGGL(gibbs_sweep, grid, block, 0, stream, X, order, h, J, beta, out);
}

// Round 3
// 5907.930 us; speedup vs baseline: 1.6464x; 1.6464x over previous
//
#include <hip/hip_runtime.h>
#include <stdint.h>
#include <math.h>

// plmDCA one Gibbs sweep — bitwise-faithful replay of the JAX reference.
// Confirmed (round 1, absmax 0.0): partitionable threefry (o0^o1), Eigen
// KC=288 k-blocked left-fold sum order, f64-computed f32-rounded logs.
// Round 2 lesson: 1024 desynced blocks thrash L2/L3 on the J gather
// (FETCH 0.54 -> 10.9 GB). Geometry must stay 256 blocks / 1 per CU so all
// CUs walk the same J row together (451 KB, L2-resident).
//
// Round 3 = round-1 geometry (SPB=32, 672 thr) + round-2 cheap inner loop
// (packed states, constexpr KC table, full unroll) + LDS-cached threefry keys.

#define NSEQ 8192
#define LRES 256
#define QST  21
#define SPB  32                // sequences per block
#define NTHREADS (SPB * QST)   // 672

// Per-l KC-crossing table: 255 = plain add; else threshold on b for boundary m.
struct KcTbl {
  unsigned char thr[LRES];
  constexpr KcTbl() : thr() {
    for (int i = 0; i < LRES; ++i) thr[i] = 255;
    for (int m = 1; m < 19; ++m) {
      int l = (288 * m) / 21;
      thr[l] = (unsigned char)(288 * m - 21 * l);
    }
  }
};
static constexpr KcTbl KC_TBL{};

__device__ __forceinline__ uint32_t rotl32(uint32_t v, uint32_t r) {
  return (v << r) | (v >> (32u - r));
}

// JAX/Random123 Threefry-2x32, 20 rounds.
__device__ __forceinline__ void threefry2x32(uint32_t k0, uint32_t k1,
                                             uint32_t c0, uint32_t c1,
                                             uint32_t& o0, uint32_t& o1) {
  uint32_t ks2 = k0 ^ k1 ^ 0x1BD11BDAu;
  uint32_t x0 = c0 + k0;
  uint32_t x1 = c1 + k1;
#define TF_ROUND(r) { x0 += x1; x1 = rotl32(x1, r); x1 ^= x0; }
  TF_ROUND(13u) TF_ROUND(15u) TF_ROUND(26u) TF_ROUND(6u)
  x0 += k1;  x1 += ks2 + 1u;
  TF_ROUND(17u) TF_ROUND(29u) TF_ROUND(16u) TF_ROUND(24u)
  x0 += ks2; x1 += k0 + 2u;
  TF_ROUND(13u) TF_ROUND(15u) TF_ROUND(26u) TF_ROUND(6u)
  x0 += k0;  x1 += k1 + 3u;
  TF_ROUND(17u) TF_ROUND(29u) TF_ROUND(16u) TF_ROUND(24u)
  x0 += k1;  x1 += ks2 + 4u;
  TF_ROUND(13u) TF_ROUND(15u) TF_ROUND(26u) TF_ROUND(6u)
  x0 += ks2; x1 += k0 + 5u;
#undef TF_ROUND
  o0 = x0; o1 = x1;
}

// JAX gumbel: -log(-log(uniform(tiny,1))), logs f64-computed f32-rounded.
__device__ __forceinline__ float gumbel_f32(uint32_t bits) {
  float f = __uint_as_float((bits >> 9) | 0x3f800000u) - 1.0f;
  float u = fmaxf(1.17549435e-38f, f + 1.17549435e-38f);
  float w = (float)log((double)u);
  float t = -w;
  float g = -(float)log((double)t);
  return g;
}

__global__ __launch_bounds__(NTHREADS)
void gibbs_sweep(const float* __restrict__ X, const int* __restrict__ order,
                 const float* __restrict__ h, const float* __restrict__ J,
                 const float* __restrict__ betaPtr, float* __restrict__ out) {
  __shared__ uint32_t sbst[(LRES / 4) * SPB];  // packed states: word (l>>2)*SPB+s
  __shared__ float    vals[QST][SPB];
  __shared__ uint32_t tk0[LRES], tk1[LRES];    // per-step threefry keys

  const int nl  = threadIdx.x;       // 0..31  local sequence
  const int a   = threadIdx.y;       // 0..20  category
  const int tid = nl + SPB * a;      // 0..671
  const int n0  = blockIdx.x * SPB;
  const int n   = n0 + nl;
  const float beta = betaPtr[0];

  // ---- per-step keys: keys[t] = threefry((0,42),(0,t)) ----
  for (int t = tid; t < LRES; t += NTHREADS) {
    uint32_t o0, o1;
    threefry2x32(0u, 42u, 0u, (uint32_t)t, o0, o1);
    tk0[t] = o0; tk1[t] = o1;
  }

  // ---- init packed state from one-hot X ----
  for (int idx = tid; idx < (LRES / 4) * SPB; idx += NTHREADS) {
    int s  = idx & (SPB - 1);
    int wg = idx / SPB;              // word group: covers l = 4wg..4wg+3
    uint32_t w = 0;
#pragma unroll
    for (int j = 0; j < 4; ++j) {
      int l = 4 * wg + j;
      const float* xp = X + ((size_t)(n0 + s) * LRES + l) * QST;
      int b = 0;
#pragma unroll
      for (int q = 0; q < QST; ++q) b = (xp[q] > 0.5f) ? q : b;
      w |= ((uint32_t)b) << (8 * j);
    }
    sbst[wg * SPB + s] = w;
  }
  __syncthreads();

  // ---- sequential Gibbs sweep ----
  for (int t = 0; t < LRES; ++t) {
    const int i = order[t];
    const uint32_t rowoff = (uint32_t)(i * QST + a) * (uint32_t)(LRES * QST);

    // dot over l, Eigen KC=288 k-blocked left-fold order.
    float tot = 0.0f, part = 0.0f;
#pragma unroll
    for (int lg = 0; lg < LRES / 4; ++lg) {
      uint32_t w = sbst[lg * SPB + nl];
#pragma unroll
      for (int j = 0; j < 4; ++j) {
        const int l = 4 * lg + j;
        uint32_t b = (w >> (8 * j)) & 0xffu;
        float jv = J[rowoff + (uint32_t)(l * QST) + b];
        const int thr = KC_TBL.thr[l];          // folds at compile time
        if (thr == 255) {
          part += jv;
        } else if (thr == 0) {                  // exact boundary
          tot += part; part = jv;
        } else {
          if ((int)b >= thr) { tot += part; part = jv; }
          else               { part += jv; tot += part; part = 0.0f; }
        }
      }
    }
    tot += part;

    float lo = h[i * QST + a] + tot;

    uint32_t o0, o1;
    threefry2x32(tk0[t], tk1[t], 0u, (uint32_t)(n * QST + a), o0, o1);
    float g = gumbel_f32(o0 ^ o1);

    vals[a][nl] = g + beta * lo;
    __syncthreads();

    if (a == 0) {                               // first-max argmax over 21
      float best = vals[0][nl];
      int bi = 0;
#pragma unroll
      for (int q = 1; q < QST; ++q) {
        float vv = vals[q][nl];
        if (vv > best) { best = vv; bi = q; }
      }
      // byte-update packed state for residue i, sequence nl
      unsigned char* bp = reinterpret_cast<unsigned char*>(sbst);
      bp[((i >> 2) * SPB + nl) * 4 + (i & 3)] = (unsigned char)bi;
    }
    __syncthreads();
  }

  // ---- expand packed state to one-hot f32 output ----
  const size_t base = (size_t)n0 * LRES * QST;
  for (int idx = tid; idx < SPB * LRES * QST; idx += NTHREADS) {
    int s   = idx / (LRES * QST);
    int rem = idx - s * (LRES * QST);
    int l   = rem / QST;
    int q   = rem - l * QST;
    uint32_t w = sbst[(l >> 2) * SPB + s];
    int b = (int)((w >> (8 * (l & 3))) & 0xffu);
    out[base + idx] = (b == q) ? 1.0f : 0.0f;
  }
}

extern "C" void kernel_launch(void* const* d_in, const int* in_sizes, int n_in,
                              void* d_out, int out_size, void* d_ws, size_t ws_size,
                              hipStream_t stream) {
  const float* X     = (const float*)d_in[0];
  const int*   order = (const int*)  d_in[1];
  const float* h     = (const float*)d_in[2];
  const float* J     = (const float*)d_in[3];
  const float* beta  = (const float*)d_in[4];
  float* out = (float*)d_out;

  dim3 grid(NSEQ / SPB);      // 256 blocks, 1 per CU
  dim3 block(SPB, QST);       // 32 x 21 = 672 threads
  hipLaunchKernelGGL(gibbs_sweep, grid, block, 0, stream, X, order, h, J, beta, out);
}